// Round 3
// baseline (115.602 us; speedup 1.0000x reference)
//
#include <hip/hip_runtime.h>
#include <math.h>

// Problem constants (fixed by setup_inputs)
#define B_     32
#define K_     16
#define T_     30
#define KT_    480      // K*T pred points per batch
#define N_     128
#define NPN_   20       // nodes per polyline
#define NODES_ 2560     // N*NPN per batch
#define CH_    32       // node chunks per batch
#define CSZ_   80       // nodes per chunk = 4 whole polylines (yaw local)

#define PI_F      3.14159265358979323846f
#define TWO_PI_F  6.28318530717958647692f
#define YAW_TH_F  (PI_F / 3.0f)

// ws layout: float ws_part[B_][CH_][KT_]  (1.97 MB), then uint ctr[B_]
#define WS_PART_ELEMS (B_ * CH_ * KT_)

// Kernel 0: zero the per-batch arrival counters (cannot rely on poison bits).
__global__ __launch_bounds__(64) void cm_init(unsigned int* __restrict__ ctr) {
  if (threadIdx.x < B_) ctr[threadIdx.x] = 0u;
}

// Kernel 1: fully fused. Per (batch, chunk) block:
//   - prep this chunk's 80 nodes into LDS as (-2x, -2y, a2|inf, yaw)
//   - prep this thread's 2 pred points in registers (redundant x32, ~3% cost)
//   - 80-node x 2-point min loop (cost' = sqrt(max(d2,4)) + relu(|dyaw|w - pi/3),
//     the -2 is hoisted out of the min)
//   - store partial mins; last block per batch reduces and writes out.
__global__ __launch_bounds__(256) void cm_fused(
    const float* __restrict__ preds,   // (B, K, T, 2)
    const float* __restrict__ cn,      // (B, N, n, 2)
    const int*   __restrict__ cmask,   // (B, N, n)
    float*        __restrict__ ws_part,
    unsigned int* __restrict__ ctr,
    float*        __restrict__ out)
{
  const int b   = blockIdx.x >> 5;          // / CH_
  const int c   = blockIdx.x & (CH_ - 1);
  const int tid = threadIdx.x;

  __shared__ float4 nd[CSZ_];
  __shared__ int    s_last;
  __shared__ float  sc[KT_];

  // ---- node prep (each chunk prepped exactly once globally) ----
  if (tid < CSZ_) {
    const int gn = c * CSZ_ + tid;
    const int j  = gn % NPN_;
    const float2* cnb = (const float2*)cn + (size_t)b * NODES_;
    const float2 p = cnb[gn];
    float yaw = 0.0f;
    if (j != 0) {
      const float2 q = cnb[gn - 1];
      yaw = -atan2f(p.x - q.x, p.y - q.y);    // ref: -arctan2(dx, dy)
    }
    const int mv = cmask[(size_t)b * NODES_ + gn];
    const float a2 = (mv == 1) ? INFINITY : fmaf(p.x, p.x, p.y * p.y);
    nd[tid] = make_float4(-2.0f * p.x, -2.0f * p.y, a2, yaw);
  }

  // ---- point prep in registers (2 points per thread) ----
  const int kt0 = tid;
  const int kt1 = tid + 256;                  // valid iff < 480
  const float2* pb = (const float2*)preds + (size_t)b * KT_;
  float4 p0, p1;
  {
    const float2 pp = pb[kt0];
    float pyaw = 0.0f;
    if ((kt0 % T_) != 0) {
      const float2 pq = pb[kt0 - 1];
      pyaw = -atan2f(pp.x - pq.x, pp.y - pq.y);
    }
    p0 = make_float4(pp.x, pp.y, fmaf(pp.x, pp.x, pp.y * pp.y), pyaw);
  }
  if (kt1 < KT_) {
    const float2 pp = pb[kt1];
    float pyaw = 0.0f;
    if ((kt1 % T_) != 0) {
      const float2 pq = pb[kt1 - 1];
      pyaw = -atan2f(pp.x - pq.x, pp.y - pq.y);
    }
    p1 = make_float4(pp.x, pp.y, fmaf(pp.x, pp.x, pp.y * pp.y), pyaw);
  } else {
    p1 = make_float4(0.f, 0.f, 0.f, 0.f);
  }

  __syncthreads();

  // ---- main min loop ----
  float m0 = INFINITY, m1 = INFINITY;
  #pragma unroll 8
  for (int i = 0; i < CSZ_; ++i) {
    const float4 nv = nd[i];                  // broadcast, conflict-free
    {
      float t = nv.z + p0.z;
      t = fmaf(nv.x, p0.x, t);
      t = fmaf(nv.y, p0.y, t);
      t = fmaxf(t, 4.0f);
      const float s  = __builtin_amdgcn_sqrtf(t);
      const float yd = nv.w - p0.w;
      const float a  = fminf(fabsf(yd), TWO_PI_F - fabsf(yd));
      const float yc = fmaxf(a - YAW_TH_F, 0.0f);
      m0 = fminf(m0, s + yc);
    }
    {
      float t = nv.z + p1.z;
      t = fmaf(nv.x, p1.x, t);
      t = fmaf(nv.y, p1.y, t);
      t = fmaxf(t, 4.0f);
      const float s  = __builtin_amdgcn_sqrtf(t);
      const float yd = nv.w - p1.w;
      const float a  = fminf(fabsf(yd), TWO_PI_F - fabsf(yd));
      const float yc = fmaxf(a - YAW_TH_F, 0.0f);
      m1 = fminf(m1, s + yc);
    }
  }

  // ---- publish partials ----
  float* wp = ws_part + ((size_t)b * CH_ + c) * KT_;
  wp[kt0] = m0;
  if (kt1 < KT_) wp[kt1] = m1;

  __syncthreads();                            // all block stores issued
  if (tid == 0) {
    __threadfence();                          // release stores device-wide
    const unsigned int prev = __hip_atomic_fetch_add(
        &ctr[b], 1u, __ATOMIC_ACQ_REL, __HIP_MEMORY_SCOPE_AGENT);
    s_last = (prev == CH_ - 1) ? 1 : 0;
  }
  __syncthreads();
  if (!s_last) return;

  // ---- last block for this batch: reduce over chunks, sum over T ----
  __threadfence();                            // acquire
  for (int kt = tid; kt < KT_; kt += 256) {
    const float* col = ws_part + (size_t)b * CH_ * KT_ + kt;
    float m = INFINITY;
    #pragma unroll
    for (int cc = 0; cc < CH_; ++cc) {
      // agent-scope load: correct across non-coherent per-XCD L2s
      const float v = __hip_atomic_load(col + cc * KT_,
                                        __ATOMIC_RELAXED,
                                        __HIP_MEMORY_SCOPE_AGENT);
      m = fminf(m, v);
    }
    sc[kt] = m - 2.0f;                        // restore hoisted -2
  }
  __syncthreads();
  if (tid < K_) {
    float s = 0.0f;
    #pragma unroll
    for (int t = 0; t < T_; ++t) s += sc[tid * T_ + t];
    out[b * K_ + tid] = s;
  }
}

extern "C" void kernel_launch(void* const* d_in, const int* in_sizes, int n_in,
                              void* d_out, int out_size, void* d_ws, size_t ws_size,
                              hipStream_t stream) {
  const float* preds = (const float*)d_in[0];
  const float* cn    = (const float*)d_in[1];
  const int*   cmask = (const int*)d_in[2];
  float* out = (float*)d_out;
  float* ws_part = (float*)d_ws;
  unsigned int* ctr = (unsigned int*)(ws_part + WS_PART_ELEMS);

  cm_init<<<dim3(1), dim3(64), 0, stream>>>(ctr);
  cm_fused<<<dim3(B_ * CH_), dim3(256), 0, stream>>>(
      preds, cn, cmask, ws_part, ctr, out);
}

// Round 4
// 73.086 us; speedup vs baseline: 1.5817x; 1.5817x over previous
//
#include <hip/hip_runtime.h>
#include <math.h>

// Problem constants (fixed by setup_inputs)
#define B_     32
#define K_     16
#define T_     30
#define KT_    480      // K*T pred points per batch
#define N_     128
#define NPN_   20       // nodes per polyline
#define NODES_ 2560     // N*NPN per batch
#define CH_    32       // node chunks per batch
#define CSZ_   80       // nodes per chunk = 4 whole polylines (yaw local)

#define PI_F      3.14159265358979323846f
#define TWO_PI_F  6.28318530717958647692f
#define YAW_TH_F  (PI_F / 3.0f)

// ws layout: float ws_part[B_][CH_][KT_]  (1.97 MB)
// NOTE (R3 post-mortem): do NOT do single-kernel cross-block reduction here —
// device-scope fences/atomics cost ~60us on gfx950 (per-XCD L2 writeback).
// The 2-kernel split is ~5us. Keep the split.

// Kernel 1: fused prep + partial min. Per (batch, chunk) block:
//   - prep this chunk's 80 nodes into LDS as (-2x, -2y, a2|inf, yaw)
//     (each chunk prepped exactly once globally)
//   - prep this thread's 2 pred points in registers (redundant x32, ~3%)
//   - 80-node x 2-point min loop:
//       cost' = sqrt(max(d2,4)) + relu(|dyaw|_wrap - pi/3)   [-2 hoisted]
//   - coalesced store of partials to ws_part[b][c][kt]
__global__ __launch_bounds__(256) void cm_main(
    const float* __restrict__ preds,   // (B, K, T, 2)
    const float* __restrict__ cn,      // (B, N, n, 2)
    const int*   __restrict__ cmask,   // (B, N, n)
    float*       __restrict__ ws_part) // (B, CH, KT)
{
  const int b   = blockIdx.x >> 5;          // / CH_
  const int c   = blockIdx.x & (CH_ - 1);
  const int tid = threadIdx.x;

  __shared__ float4 nd[CSZ_];

  // ---- node prep ----
  if (tid < CSZ_) {
    const int gn = c * CSZ_ + tid;
    const int j  = gn % NPN_;
    const float2* cnb = (const float2*)cn + (size_t)b * NODES_;
    const float2 p = cnb[gn];
    float yaw = 0.0f;
    if (j != 0) {
      const float2 q = cnb[gn - 1];
      yaw = -atan2f(p.x - q.x, p.y - q.y);    // ref: -arctan2(dx, dy)
    }
    const int mv = cmask[(size_t)b * NODES_ + gn];
    const float a2 = (mv == 1) ? INFINITY : fmaf(p.x, p.x, p.y * p.y);
    nd[tid] = make_float4(-2.0f * p.x, -2.0f * p.y, a2, yaw);
  }

  // ---- point prep in registers (2 points per thread) ----
  const int kt0 = tid;
  const int kt1 = tid + 256;                  // valid iff < 480
  const float2* pb = (const float2*)preds + (size_t)b * KT_;
  float4 p0, p1;
  {
    const float2 pp = pb[kt0];
    float pyaw = 0.0f;
    if ((kt0 % T_) != 0) {
      const float2 pq = pb[kt0 - 1];
      pyaw = -atan2f(pp.x - pq.x, pp.y - pq.y);
    }
    p0 = make_float4(pp.x, pp.y, fmaf(pp.x, pp.x, pp.y * pp.y), pyaw);
  }
  if (kt1 < KT_) {
    const float2 pp = pb[kt1];
    float pyaw = 0.0f;
    if ((kt1 % T_) != 0) {
      const float2 pq = pb[kt1 - 1];
      pyaw = -atan2f(pp.x - pq.x, pp.y - pq.y);
    }
    p1 = make_float4(pp.x, pp.y, fmaf(pp.x, pp.x, pp.y * pp.y), pyaw);
  } else {
    p1 = make_float4(0.f, 0.f, 0.f, 0.f);     // benign garbage lane
  }

  __syncthreads();

  // ---- main min loop ----
  float m0 = INFINITY, m1 = INFINITY;
  #pragma unroll 8
  for (int i = 0; i < CSZ_; ++i) {
    const float4 nv = nd[i];                  // broadcast, conflict-free
    {
      float t = nv.z + p0.z;
      t = fmaf(nv.x, p0.x, t);
      t = fmaf(nv.y, p0.y, t);
      t = fmaxf(t, 4.0f);
      const float s  = __builtin_amdgcn_sqrtf(t);
      const float yd = nv.w - p0.w;
      const float a  = fminf(fabsf(yd), TWO_PI_F - fabsf(yd));
      const float yc = fmaxf(a - YAW_TH_F, 0.0f);
      m0 = fminf(m0, s + yc);
    }
    {
      float t = nv.z + p1.z;
      t = fmaf(nv.x, p1.x, t);
      t = fmaf(nv.y, p1.y, t);
      t = fmaxf(t, 4.0f);
      const float s  = __builtin_amdgcn_sqrtf(t);
      const float yd = nv.w - p1.w;
      const float a  = fminf(fabsf(yd), TWO_PI_F - fabsf(yd));
      const float yc = fmaxf(a - YAW_TH_F, 0.0f);
      m1 = fminf(m1, s + yc);
    }
  }

  float* wp = ws_part + ((size_t)b * CH_ + c) * KT_;
  wp[kt0] = m0;
  if (kt1 < KT_) wp[kt1] = m1;
}

// Kernel 2: min over chunks (coalesced), subtract hoisted 2, sum over T.
__global__ __launch_bounds__(512) void cm_reduce(
    const float* __restrict__ ws_part, float* __restrict__ out)
{
  const int b   = blockIdx.x;
  const int tid = threadIdx.x;
  __shared__ float sc[KT_];

  if (tid < KT_) {
    const float* wp = ws_part + (size_t)b * CH_ * KT_;
    float m = INFINITY;
    #pragma unroll
    for (int c = 0; c < CH_; ++c) m = fminf(m, wp[c * KT_ + tid]);
    sc[tid] = m - 2.0f;                       // restore the hoisted -2
  }
  __syncthreads();

  if (tid < K_) {
    float s = 0.0f;
    #pragma unroll
    for (int t = 0; t < T_; ++t) s += sc[tid * T_ + t];
    out[b * K_ + tid] = s;
  }
}

extern "C" void kernel_launch(void* const* d_in, const int* in_sizes, int n_in,
                              void* d_out, int out_size, void* d_ws, size_t ws_size,
                              hipStream_t stream) {
  const float* preds = (const float*)d_in[0];
  const float* cn    = (const float*)d_in[1];
  const int*   cmask = (const int*)d_in[2];
  float* out = (float*)d_out;
  float* ws_part = (float*)d_ws;

  cm_main<<<dim3(B_ * CH_), dim3(256), 0, stream>>>(preds, cn, cmask, ws_part);
  cm_reduce<<<dim3(B_), dim3(512), 0, stream>>>(ws_part, out);
}

// Round 5
// 69.698 us; speedup vs baseline: 1.6586x; 1.0486x over previous
//
#include <hip/hip_runtime.h>
#include <math.h>

// Problem constants (fixed by setup_inputs)
#define B_     32
#define K_     16
#define T_     30
#define KT_    480      // K*T pred points per batch
#define N_     128
#define NPN_   20       // nodes per polyline
#define NODES_ 2560     // N*NPN per batch
#define CH_    32       // node chunks per batch
#define CSZ_   80       // nodes per chunk = 4 whole polylines (yaw local)

#define PI_F      3.14159265358979323846f
#define TWO_PI_F  6.28318530717958647692f
#define YAW_TH_F  (PI_F / 3.0f)

// ws layout: float ws_part[B_][CH_][KT_]  (1.97 MB)
// R3 post-mortem: NO single-kernel cross-block reduction — device-scope
// fences/atomics cost ~60us on gfx950 (per-XCD L2 writeback). Keep 2 kernels.
// R5: ~50% of nodes are masked (randint 0..1). min is commutative -> compact
// each chunk's unmasked nodes in LDS (order-free via LDS atomic counter) and
// loop over ~44 instead of 80.

__global__ __launch_bounds__(256) void cm_main(
    const float* __restrict__ preds,   // (B, K, T, 2)
    const float* __restrict__ cn,      // (B, N, n, 2)
    const int*   __restrict__ cmask,   // (B, N, n)
    float*       __restrict__ ws_part) // (B, CH, KT)
{
  const int b   = blockIdx.x >> 5;          // / CH_
  const int c   = blockIdx.x & (CH_ - 1);
  const int tid = threadIdx.x;

  __shared__ float4 nd[CSZ_ + 8];   // compacted (-2x, -2y, a2, yaw) + inf pad
  __shared__ int    s_cnt;

  if (tid == 0) s_cnt = 0;
  __syncthreads();

  // ---- node prep + compaction (only unmasked nodes enter LDS) ----
  if (tid < CSZ_) {
    const int gn = c * CSZ_ + tid;
    const int mv = cmask[(size_t)b * NODES_ + gn];
    if (mv != 1) {
      const int j = gn % NPN_;
      const float2* cnb = (const float2*)cn + (size_t)b * NODES_;
      const float2 p = cnb[gn];
      float yaw = 0.0f;
      if (j != 0) {
        const float2 q = cnb[gn - 1];
        yaw = -atan2f(p.x - q.x, p.y - q.y);  // ref: -arctan2(dx, dy)
      }
      const float a2 = fmaf(p.x, p.x, p.y * p.y);
      const int pos = atomicAdd(&s_cnt, 1);   // LDS atomic, order-free for min
      nd[pos] = make_float4(-2.0f * p.x, -2.0f * p.y, a2, yaw);
    }
  }

  // ---- point prep in registers (2 points per thread) ----
  const int kt0 = tid;
  const int kt1 = tid + 256;                  // valid iff < 480
  const float2* pb = (const float2*)preds + (size_t)b * KT_;
  float4 p0, p1;
  {
    const float2 pp = pb[kt0];
    float pyaw = 0.0f;
    if ((kt0 % T_) != 0) {
      const float2 pq = pb[kt0 - 1];
      pyaw = -atan2f(pp.x - pq.x, pp.y - pq.y);
    }
    p0 = make_float4(pp.x, pp.y, fmaf(pp.x, pp.x, pp.y * pp.y), pyaw);
  }
  if (kt1 < KT_) {
    const float2 pp = pb[kt1];
    float pyaw = 0.0f;
    if ((kt1 % T_) != 0) {
      const float2 pq = pb[kt1 - 1];
      pyaw = -atan2f(pp.x - pq.x, pp.y - pq.y);
    }
    p1 = make_float4(pp.x, pp.y, fmaf(pp.x, pp.x, pp.y * pp.y), pyaw);
  } else {
    p1 = make_float4(0.f, 0.f, 0.f, 0.f);     // benign garbage lane
  }

  __syncthreads();
  const int cnt  = s_cnt;
  const int npad = (cnt + 7) & ~7;            // round up to unroll factor
  if (tid < npad - cnt)                       // inf sentinels: min no-ops
    nd[cnt + tid] = make_float4(0.f, 0.f, INFINITY, 0.f);
  __syncthreads();

  // ---- main min loop over compacted nodes ----
  float m0 = INFINITY, m1 = INFINITY;
  for (int i = 0; i < npad; i += 8) {
    #pragma unroll
    for (int j = 0; j < 8; ++j) {
      const float4 nv = nd[i + j];            // broadcast, conflict-free
      {
        float t = nv.z + p0.z;
        t = fmaf(nv.x, p0.x, t);
        t = fmaf(nv.y, p0.y, t);
        t = fmaxf(t, 4.0f);
        const float s  = __builtin_amdgcn_sqrtf(t);
        const float yd = nv.w - p0.w;
        const float a  = fminf(fabsf(yd), TWO_PI_F - fabsf(yd));
        const float yc = fmaxf(a - YAW_TH_F, 0.0f);
        m0 = fminf(m0, s + yc);
      }
      {
        float t = nv.z + p1.z;
        t = fmaf(nv.x, p1.x, t);
        t = fmaf(nv.y, p1.y, t);
        t = fmaxf(t, 4.0f);
        const float s  = __builtin_amdgcn_sqrtf(t);
        const float yd = nv.w - p1.w;
        const float a  = fminf(fabsf(yd), TWO_PI_F - fabsf(yd));
        const float yc = fmaxf(a - YAW_TH_F, 0.0f);
        m1 = fminf(m1, s + yc);
      }
    }
  }

  float* wp = ws_part + ((size_t)b * CH_ + c) * KT_;
  wp[kt0] = m0;
  if (kt1 < KT_) wp[kt1] = m1;
}

// Kernel 2: min over chunks (coalesced), subtract hoisted 2, sum over T.
__global__ __launch_bounds__(512) void cm_reduce(
    const float* __restrict__ ws_part, float* __restrict__ out)
{
  const int b   = blockIdx.x;
  const int tid = threadIdx.x;
  __shared__ float sc[KT_];

  if (tid < KT_) {
    const float* wp = ws_part + (size_t)b * CH_ * KT_;
    float m = INFINITY;
    #pragma unroll
    for (int c = 0; c < CH_; ++c) m = fminf(m, wp[c * KT_ + tid]);
    sc[tid] = m - 2.0f;                       // restore the hoisted -2
  }
  __syncthreads();

  if (tid < K_) {
    float s = 0.0f;
    #pragma unroll
    for (int t = 0; t < T_; ++t) s += sc[tid * T_ + t];
    out[b * K_ + tid] = s;
  }
}

extern "C" void kernel_launch(void* const* d_in, const int* in_sizes, int n_in,
                              void* d_out, int out_size, void* d_ws, size_t ws_size,
                              hipStream_t stream) {
  const float* preds = (const float*)d_in[0];
  const float* cn    = (const float*)d_in[1];
  const int*   cmask = (const int*)d_in[2];
  float* out = (float*)d_out;
  float* ws_part = (float*)d_ws;

  cm_main<<<dim3(B_ * CH_), dim3(256), 0, stream>>>(preds, cn, cmask, ws_part);
  cm_reduce<<<dim3(B_), dim3(512), 0, stream>>>(ws_part, out);
}